// Round 3
// baseline (1775.343 us; speedup 1.0000x reference)
//
#include <hip/hip_runtime.h>

// GCN 2-layer, bucket-LDS-accumulate strategy.
// Edges bucketed by dst>>8 (391 buckets x 256 nodes). Aggregation per bucket:
// LDS accumulators (256 nodes x feat), per-edge gather + ds_add_f32.
// No global fp32 atomics (R1: write-through, 400 MB), no per-node sort
// (R2: 105 MB random scatter). Cursor atomics hit only 391 addresses.

#define BSHIFT 8
#define BNODES 256
#define CHUNK 2048

__global__ __launch_bounds__(256) void hist_kernel(
    const int* __restrict__ dst, int E, int* __restrict__ bcnt, int B) {
    __shared__ int h[512];
    int t = threadIdx.x;
    for (int i = t; i < 512; i += 256) h[i] = 0;
    __syncthreads();
    int per = (E + gridDim.x - 1) / gridDim.x;
    int lo = blockIdx.x * per;
    int hi = min(lo + per, E);
    for (int i = lo + t; i < hi; i += 256) atomicAdd(&h[dst[i] >> BSHIFT], 1);
    __syncthreads();
    for (int i = t; i < B; i += 256)
        if (h[i]) atomicAdd(&bcnt[i], h[i]);
}

// Exclusive scan of bucket counts (B <= 512), one block.
__global__ __launch_bounds__(512) void scan_kernel(
    const int* __restrict__ bcnt, int* __restrict__ base,
    int* __restrict__ cursor, int B, int E) {
    __shared__ int s[512];
    int t = threadIdx.x;
    int v0 = (t < B) ? bcnt[t] : 0;
    s[t] = v0;
    __syncthreads();
#pragma unroll
    for (int d = 1; d < 512; d <<= 1) {
        int v = (t >= d) ? s[t - d] : 0;
        __syncthreads();
        s[t] += v;
        __syncthreads();
    }
    if (t < B) {
        int e = s[t] - v0;
        base[t] = e;
        cursor[t] = e;
    }
    if (t == 0) base[B] = E;
}

// Bucket edges: packed = (src<<8)|dstLocal, grouped by bucket.
__global__ void scatter_kernel(const int* __restrict__ src,
                               const int* __restrict__ dst,
                               int* __restrict__ cursor,
                               int* __restrict__ packed, int E) {
    int e = blockIdx.x * 256 + threadIdx.x;
    if (e < E) {
        int d = dst[e];
        int pos = atomicAdd(&cursor[d >> BSHIFT], 1);
        packed[pos] = (src[e] << BSHIFT) | (d & (BNODES - 1));
    }
}

// Per-bucket degree histogram -> dinv = rsqrt(deg+1). No global atomics.
__global__ __launch_bounds__(256) void dinv_kernel(
    const int* __restrict__ packed, const int* __restrict__ base,
    float* __restrict__ dinv, int N) {
    __shared__ int cnt[BNODES];
    int t = threadIdx.x, b = blockIdx.x;
    cnt[t] = 0;
    __syncthreads();
    int lo = base[b], hi = base[b + 1];
    for (int i = lo + t; i < hi; i += 256)
        atomicAdd(&cnt[packed[i] & (BNODES - 1)], 1);
    __syncthreads();
    int node = (b << BSHIFT) + t;
    if (node < N) dinv[node] = rsqrtf((float)(cnt[t] + 1));
}

// hs = (x@W1)*dinv. 2 rows/thread to halve LDS broadcast reads.
__global__ __launch_bounds__(256) void gemm1_kernel(
    const float* __restrict__ x, const float* __restrict__ W1,
    const float* __restrict__ dinv, float* __restrict__ hs, int N) {
    __shared__ float4 Ws[64 * 16];
    int t = threadIdx.x;
    const float4* W4 = (const float4*)W1;
    for (int i = t; i < 1024; i += 256) Ws[i] = W4[i];
    __syncthreads();
    int ra = blockIdx.x * 512 + t;
    int rb = ra + 256;
    if (ra >= N) return;
    bool hb = rb < N;
    const float4* xa = (const float4*)(x + (size_t)ra * 64);
    const float4* xb = (const float4*)(x + (size_t)rb * 64);
    float4 acc0[16], acc1[16];
#pragma unroll
    for (int j = 0; j < 16; j++) {
        acc0[j] = make_float4(0.f, 0.f, 0.f, 0.f);
        acc1[j] = make_float4(0.f, 0.f, 0.f, 0.f);
    }
    for (int k4 = 0; k4 < 16; k4++) {
        float4 x0 = xa[k4];
        float4 x1 = hb ? xb[k4] : make_float4(0.f, 0.f, 0.f, 0.f);
#pragma unroll
        for (int kk = 0; kk < 4; kk++) {
            float a0 = ((const float*)&x0)[kk];
            float a1 = ((const float*)&x1)[kk];
            const float4* wr = &Ws[(k4 * 4 + kk) * 16];
#pragma unroll
            for (int j = 0; j < 16; j++) {
                float4 w = wr[j];
                acc0[j].x += a0 * w.x; acc0[j].y += a0 * w.y;
                acc0[j].z += a0 * w.z; acc0[j].w += a0 * w.w;
                acc1[j].x += a1 * w.x; acc1[j].y += a1 * w.y;
                acc1[j].z += a1 * w.z; acc1[j].w += a1 * w.w;
            }
        }
    }
    float d0 = dinv[ra];
    float4* ha = (float4*)(hs + (size_t)ra * 64);
#pragma unroll
    for (int j = 0; j < 16; j++) {
        float4 v = acc0[j];
        v.x *= d0; v.y *= d0; v.z *= d0; v.w *= d0;
        ha[j] = v;
    }
    if (hb) {
        float d1 = dinv[rb];
        float4* hb4 = (float4*)(hs + (size_t)rb * 64);
#pragma unroll
        for (int j = 0; j < 16; j++) {
            float4 v = acc1[j];
            v.x *= d1; v.y *= d1; v.z *= d1; v.w *= d1;
            hb4[j] = v;
        }
    }
}

// Layer-1 aggregate: bucket in LDS, h1 = relu((self + sum)*dinv + b1).
__global__ __launch_bounds__(256) void agg1_kernel(
    const float* __restrict__ hs, const int* __restrict__ packed,
    const int* __restrict__ base, const float* __restrict__ dinv,
    const float* __restrict__ b1, float* __restrict__ h1, int N) {
    __shared__ float acc[BNODES * 64];  // 64 KB
    __shared__ int eb[CHUNK];           // 8 KB
    __shared__ float b1s[64];
    int t = threadIdx.x, b = blockIdx.x;
    if (t < 64) b1s[t] = b1[t];
    int nbase = b << BSHIFT;
    for (int idx = t; idx < BNODES * 16; idx += 256) {
        int node = nbase + (idx >> 4);
        float4 v = (node < N) ? ((const float4*)hs)[(size_t)node * 16 + (idx & 15)]
                              : make_float4(0.f, 0.f, 0.f, 0.f);
        ((float4*)acc)[idx] = v;  // self-loop term
    }
    __syncthreads();
    int lo = base[b], hi = base[b + 1];
    int wv = t >> 6, l = t & 63;
    for (int c = lo; c < hi; c += CHUNK) {
        int n = min(CHUNK, hi - c);
        for (int i = t; i < n; i += 256) eb[i] = packed[c + i];
        __syncthreads();
        int i = wv;
        for (; i + 12 < n; i += 16) {
            int p0 = eb[i], p1 = eb[i + 4], p2 = eb[i + 8], p3 = eb[i + 12];
            float v0 = hs[(size_t)(p0 >> BSHIFT) * 64 + l];
            float v1 = hs[(size_t)(p1 >> BSHIFT) * 64 + l];
            float v2 = hs[(size_t)(p2 >> BSHIFT) * 64 + l];
            float v3 = hs[(size_t)(p3 >> BSHIFT) * 64 + l];
            atomicAdd(&acc[(p0 & 255) * 64 + l], v0);
            atomicAdd(&acc[(p1 & 255) * 64 + l], v1);
            atomicAdd(&acc[(p2 & 255) * 64 + l], v2);
            atomicAdd(&acc[(p3 & 255) * 64 + l], v3);
        }
        for (; i < n; i += 4) {
            int p = eb[i];
            float v = hs[(size_t)(p >> BSHIFT) * 64 + l];
            atomicAdd(&acc[(p & 255) * 64 + l], v);
        }
        __syncthreads();
    }
    for (int idx = t; idx < BNODES * 16; idx += 256) {
        int node = nbase + (idx >> 4);
        if (node < N) {
            float di = dinv[node];
            float4 v = ((float4*)acc)[idx];
            float4 bb = ((float4*)b1s)[idx & 15];
            v.x = fmaxf(v.x * di + bb.x, 0.f);
            v.y = fmaxf(v.y * di + bb.y, 0.f);
            v.z = fmaxf(v.z * di + bb.z, 0.f);
            v.w = fmaxf(v.w * di + bb.w, 0.f);
            ((float4*)h1)[(size_t)node * 16 + (idx & 15)] = v;
        }
    }
}

// gs = (h1@W2)*dinv. 2 rows/thread.
__global__ __launch_bounds__(256) void gemm2_kernel(
    const float* __restrict__ h1, const float* __restrict__ W2,
    const float* __restrict__ dinv, float* __restrict__ gs, int N) {
    __shared__ float4 Ws[64 * 8];
    int t = threadIdx.x;
    const float4* W4 = (const float4*)W2;
    for (int i = t; i < 512; i += 256) Ws[i] = W4[i];
    __syncthreads();
    int ra = blockIdx.x * 512 + t;
    int rb = ra + 256;
    if (ra >= N) return;
    bool hb = rb < N;
    const float4* xa = (const float4*)(h1 + (size_t)ra * 64);
    const float4* xb = (const float4*)(h1 + (size_t)rb * 64);
    float4 acc0[8], acc1[8];
#pragma unroll
    for (int j = 0; j < 8; j++) {
        acc0[j] = make_float4(0.f, 0.f, 0.f, 0.f);
        acc1[j] = make_float4(0.f, 0.f, 0.f, 0.f);
    }
    for (int k4 = 0; k4 < 16; k4++) {
        float4 x0 = xa[k4];
        float4 x1 = hb ? xb[k4] : make_float4(0.f, 0.f, 0.f, 0.f);
#pragma unroll
        for (int kk = 0; kk < 4; kk++) {
            float a0 = ((const float*)&x0)[kk];
            float a1 = ((const float*)&x1)[kk];
            const float4* wr = &Ws[(k4 * 4 + kk) * 8];
#pragma unroll
            for (int j = 0; j < 8; j++) {
                float4 w = wr[j];
                acc0[j].x += a0 * w.x; acc0[j].y += a0 * w.y;
                acc0[j].z += a0 * w.z; acc0[j].w += a0 * w.w;
                acc1[j].x += a1 * w.x; acc1[j].y += a1 * w.y;
                acc1[j].z += a1 * w.z; acc1[j].w += a1 * w.w;
            }
        }
    }
    float d0 = dinv[ra];
    float4* ga = (float4*)(gs + (size_t)ra * 32);
#pragma unroll
    for (int j = 0; j < 8; j++) {
        float4 v = acc0[j];
        v.x *= d0; v.y *= d0; v.z *= d0; v.w *= d0;
        ga[j] = v;
    }
    if (hb) {
        float d1 = dinv[rb];
        float4* gb = (float4*)(gs + (size_t)rb * 32);
#pragma unroll
        for (int j = 0; j < 8; j++) {
            float4 v = acc1[j];
            v.x *= d1; v.y *= d1; v.z *= d1; v.w *= d1;
            gb[j] = v;
        }
    }
}

// Layer-2 aggregate: feat=32, 2 edges per wave (half-wave per edge).
__global__ __launch_bounds__(256) void agg2_kernel(
    const float* __restrict__ gs, const int* __restrict__ packed,
    const int* __restrict__ base, const float* __restrict__ dinv,
    const float* __restrict__ b2, float* __restrict__ out, int N) {
    __shared__ float acc[BNODES * 32];  // 32 KB
    __shared__ int eb[CHUNK];           // 8 KB
    __shared__ float b2s[32];
    int t = threadIdx.x, b = blockIdx.x;
    if (t < 32) b2s[t] = b2[t];
    int nbase = b << BSHIFT;
    for (int idx = t; idx < BNODES * 8; idx += 256) {
        int node = nbase + (idx >> 3);
        float4 v = (node < N) ? ((const float4*)gs)[(size_t)node * 8 + (idx & 7)]
                              : make_float4(0.f, 0.f, 0.f, 0.f);
        ((float4*)acc)[idx] = v;  // self-loop term
    }
    __syncthreads();
    int lo = base[b], hi = base[b + 1];
    int sub = t >> 5;  // 0..7 half-wave slot
    int l = t & 31;
    for (int c = lo; c < hi; c += CHUNK) {
        int n = min(CHUNK, hi - c);
        for (int i = t; i < n; i += 256) eb[i] = packed[c + i];
        __syncthreads();
        int i = sub;
        for (; i + 24 < n; i += 32) {
            int p0 = eb[i], p1 = eb[i + 8], p2 = eb[i + 16], p3 = eb[i + 24];
            float v0 = gs[(size_t)(p0 >> BSHIFT) * 32 + l];
            float v1 = gs[(size_t)(p1 >> BSHIFT) * 32 + l];
            float v2 = gs[(size_t)(p2 >> BSHIFT) * 32 + l];
            float v3 = gs[(size_t)(p3 >> BSHIFT) * 32 + l];
            atomicAdd(&acc[(p0 & 255) * 32 + l], v0);
            atomicAdd(&acc[(p1 & 255) * 32 + l], v1);
            atomicAdd(&acc[(p2 & 255) * 32 + l], v2);
            atomicAdd(&acc[(p3 & 255) * 32 + l], v3);
        }
        for (; i < n; i += 8) {
            int p = eb[i];
            float v = gs[(size_t)(p >> BSHIFT) * 32 + l];
            atomicAdd(&acc[(p & 255) * 32 + l], v);
        }
        __syncthreads();
    }
    for (int idx = t; idx < BNODES * 8; idx += 256) {
        int node = nbase + (idx >> 3);
        if (node < N) {
            float di = dinv[node];
            float4 v = ((float4*)acc)[idx];
            float4 bb = ((float4*)b2s)[idx & 7];
            v.x = v.x * di + bb.x;
            v.y = v.y * di + bb.y;
            v.z = v.z * di + bb.z;
            v.w = v.w * di + bb.w;
            ((float4*)out)[(size_t)node * 8 + (idx & 7)] = v;
        }
    }
}

extern "C" void kernel_launch(void* const* d_in, const int* in_sizes, int n_in,
                              void* d_out, int out_size, void* d_ws,
                              size_t ws_size, hipStream_t stream) {
    const float* x  = (const float*)d_in[0];
    const int* ei   = (const int*)d_in[1];
    const float* W1 = (const float*)d_in[2];
    const float* b1 = (const float*)d_in[3];
    const float* W2 = (const float*)d_in[4];
    const float* b2 = (const float*)d_in[5];
    int N = in_sizes[0] / 64;
    int E = in_sizes[1] / 2;
    const int* src = ei;
    const int* dst = ei + E;
    int B = (N + BNODES - 1) >> BSHIFT;  // 391 for N=100000

    char* ws = (char*)d_ws;
    size_t o = 0;
    int* bcnt    = (int*)(ws + o); o += 512 * 4;
    int* base    = (int*)(ws + o); o += 513 * 4;
    int* cursor  = (int*)(ws + o); o += 512 * 4;
    float* dinv  = (float*)(ws + o); o += (size_t)N * 4;
    int* packed  = (int*)(ws + o); o += (size_t)E * 4;
    float* hs    = (float*)(ws + o); o += (size_t)N * 64 * 4;
    float* h1    = (float*)(ws + o); o += (size_t)N * 64 * 4;
    float* gs    = hs;  // dead after agg1; reuse (N*32)
    float* outp  = (float*)d_out;

    hipMemsetAsync(bcnt, 0, 512 * 4, stream);
    hist_kernel<<<(E + 4095) / 4096, 256, 0, stream>>>(dst, E, bcnt, B);
    scan_kernel<<<1, 512, 0, stream>>>(bcnt, base, cursor, B, E);
    scatter_kernel<<<(E + 255) / 256, 256, 0, stream>>>(src, dst, cursor,
                                                        packed, E);
    dinv_kernel<<<B, 256, 0, stream>>>(packed, base, dinv, N);
    gemm1_kernel<<<(N + 511) / 512, 256, 0, stream>>>(x, W1, dinv, hs, N);
    agg1_kernel<<<B, 256, 0, stream>>>(hs, packed, base, dinv, b1, h1, N);
    gemm2_kernel<<<(N + 511) / 512, 256, 0, stream>>>(h1, W2, dinv, gs, N);
    agg2_kernel<<<B, 256, 0, stream>>>(gs, packed, base, dinv, b2, outp, N);
}

// Round 4
// 864.080 us; speedup vs baseline: 2.0546x; 2.0546x over previous
//
#include <hip/hip_runtime.h>

// GCN 2-layer. Pipeline:
//   hist -> scan -> bucket-scatter -> per-bucket LDS counting sort
//   -> gemm1 -> gather-agg1 -> gemm2 -> gather-agg2
// R1: global fp32 atomics write through (400 MB). R2: per-node sort scatters
// 105 MB. R3: per-bucket LDS accumulate caps grid at 391 blocks (14% occ,
// 711 us). This round: R2's high-parallelism gather agg + two-phase sort
// whose writes stay in 16 KB L2-resident windows.

#define BSHIFT 8
#define BNODES 256

__global__ __launch_bounds__(256) void hist_kernel(
    const int* __restrict__ dst, int E, int* __restrict__ bcnt, int B) {
    __shared__ int h[512];
    int t = threadIdx.x;
    for (int i = t; i < 512; i += 256) h[i] = 0;
    __syncthreads();
    int per = (E + gridDim.x - 1) / gridDim.x;
    int lo = blockIdx.x * per;
    int hi = min(lo + per, E);
    for (int i = lo + t; i < hi; i += 256) atomicAdd(&h[dst[i] >> BSHIFT], 1);
    __syncthreads();
    for (int i = t; i < B; i += 256)
        if (h[i]) atomicAdd(&bcnt[i], h[i]);
}

// Exclusive scan of bucket counts (B <= 512), one block. Also off[N] = E.
__global__ __launch_bounds__(512) void scan_kernel(
    const int* __restrict__ bcnt, int* __restrict__ base,
    int* __restrict__ cursor, int* __restrict__ off, int B, int E, int N) {
    __shared__ int s[512];
    int t = threadIdx.x;
    int v0 = (t < B) ? bcnt[t] : 0;
    s[t] = v0;
    __syncthreads();
#pragma unroll
    for (int d = 1; d < 512; d <<= 1) {
        int v = (t >= d) ? s[t - d] : 0;
        __syncthreads();
        s[t] += v;
        __syncthreads();
    }
    if (t < B) {
        int e = s[t] - v0;
        base[t] = e;
        cursor[t] = e;
    }
    if (t == 0) {
        base[B] = E;
        off[N] = E;
    }
}

// Bucket edges: packed = (src<<8)|dstLocal, grouped by dst>>8.
// Cursor atomics hit only B (=391) addresses; writes form B sequential streams.
__global__ void scatter_kernel(const int* __restrict__ src,
                               const int* __restrict__ dst,
                               int* __restrict__ cursor,
                               int* __restrict__ packed, int E) {
    int e = blockIdx.x * 256 + threadIdx.x;
    if (e < E) {
        int d = dst[e];
        int pos = atomicAdd(&cursor[d >> BSHIFT], 1);
        packed[pos] = (src[e] << BSHIFT) | (d & (BNODES - 1));
    }
}

// Per-bucket LDS counting sort -> ssrc grouped by node; also off & dinv.
// All global writes land in this bucket's own 16 KB window (L2-resident).
__global__ __launch_bounds__(256) void bsort_kernel(
    const int* __restrict__ packed, const int* __restrict__ base,
    int* __restrict__ ssrc, int* __restrict__ off, float* __restrict__ dinv,
    int N) {
    __shared__ int s[BNODES];
    __shared__ int cur[BNODES];
    int t = threadIdx.x, b = blockIdx.x;
    s[t] = 0;
    __syncthreads();
    int lo = base[b], hi = base[b + 1];
    for (int i = lo + t; i < hi; i += 256)
        atomicAdd(&s[packed[i] & (BNODES - 1)], 1);
    __syncthreads();
    int deg = s[t];
    __syncthreads();
    // inclusive Hillis-Steele scan over 256 bins
    s[t] = deg;
    __syncthreads();
#pragma unroll
    for (int d = 1; d < BNODES; d <<= 1) {
        int v = (t >= d) ? s[t - d] : 0;
        __syncthreads();
        s[t] += v;
        __syncthreads();
    }
    int excl = s[t] - deg;
    cur[t] = excl;
    int node = (b << BSHIFT) + t;
    if (node < N) {
        off[node] = lo + excl;
        dinv[node] = rsqrtf((float)(deg + 1));
    }
    __syncthreads();
    for (int i = lo + t; i < hi; i += 256) {
        int p = packed[i];
        int pos = atomicAdd(&cur[p & (BNODES - 1)], 1);
        ssrc[lo + pos] = p >> BSHIFT;
    }
}

// hs = (x@W1)*dinv. 2 rows/thread, W1 broadcast from LDS.
__global__ __launch_bounds__(256) void gemm1_kernel(
    const float* __restrict__ x, const float* __restrict__ W1,
    const float* __restrict__ dinv, float* __restrict__ hs, int N) {
    __shared__ float4 Ws[64 * 16];
    int t = threadIdx.x;
    const float4* W4 = (const float4*)W1;
    for (int i = t; i < 1024; i += 256) Ws[i] = W4[i];
    __syncthreads();
    int ra = blockIdx.x * 512 + t;
    int rb = ra + 256;
    if (ra >= N) return;
    bool hb = rb < N;
    const float4* xa = (const float4*)(x + (size_t)ra * 64);
    const float4* xb = (const float4*)(x + (size_t)rb * 64);
    float4 acc0[16], acc1[16];
#pragma unroll
    for (int j = 0; j < 16; j++) {
        acc0[j] = make_float4(0.f, 0.f, 0.f, 0.f);
        acc1[j] = make_float4(0.f, 0.f, 0.f, 0.f);
    }
    for (int k4 = 0; k4 < 16; k4++) {
        float4 x0 = xa[k4];
        float4 x1 = hb ? xb[k4] : make_float4(0.f, 0.f, 0.f, 0.f);
#pragma unroll
        for (int kk = 0; kk < 4; kk++) {
            float a0 = ((const float*)&x0)[kk];
            float a1 = ((const float*)&x1)[kk];
            const float4* wr = &Ws[(k4 * 4 + kk) * 16];
#pragma unroll
            for (int j = 0; j < 16; j++) {
                float4 w = wr[j];
                acc0[j].x += a0 * w.x; acc0[j].y += a0 * w.y;
                acc0[j].z += a0 * w.z; acc0[j].w += a0 * w.w;
                acc1[j].x += a1 * w.x; acc1[j].y += a1 * w.y;
                acc1[j].z += a1 * w.z; acc1[j].w += a1 * w.w;
            }
        }
    }
    float d0 = dinv[ra];
    float4* ha = (float4*)(hs + (size_t)ra * 64);
#pragma unroll
    for (int j = 0; j < 16; j++) {
        float4 v = acc0[j];
        v.x *= d0; v.y *= d0; v.z *= d0; v.w *= d0;
        ha[j] = v;
    }
    if (hb) {
        float d1 = dinv[rb];
        float4* hb4 = (float4*)(hs + (size_t)rb * 64);
#pragma unroll
        for (int j = 0; j < 16; j++) {
            float4 v = acc1[j];
            v.x *= d1; v.y *= d1; v.z *= d1; v.w *= d1;
            hb4[j] = v;
        }
    }
}

// Gather-aggregate layer 1: wave per node, lane = feature (64).
__global__ __launch_bounds__(256) void agg1_kernel(
    const float* __restrict__ hs, const int* __restrict__ ssrc,
    const int* __restrict__ off, const float* __restrict__ dinv,
    const float* __restrict__ b1, float* __restrict__ h1, int N) {
    int w = (blockIdx.x * 256 + threadIdx.x) >> 6;
    int l = threadIdx.x & 63;
    if (w >= N) return;
    float acc = hs[(size_t)w * 64 + l];  // self-loop
    int lo = off[w], hi = off[w + 1];
    int e = lo;
    for (; e + 4 <= hi; e += 4) {
        int s0 = ssrc[e + 0];
        int s1 = ssrc[e + 1];
        int s2 = ssrc[e + 2];
        int s3 = ssrc[e + 3];
        float v0 = hs[(size_t)s0 * 64 + l];
        float v1 = hs[(size_t)s1 * 64 + l];
        float v2 = hs[(size_t)s2 * 64 + l];
        float v3 = hs[(size_t)s3 * 64 + l];
        acc += (v0 + v1) + (v2 + v3);
    }
    for (; e < hi; e++) {
        int s = ssrc[e];
        acc += hs[(size_t)s * 64 + l];
    }
    h1[(size_t)w * 64 + l] = fmaxf(acc * dinv[w] + b1[l], 0.f);
}

// gs = (h1@W2)*dinv. 2 rows/thread.
__global__ __launch_bounds__(256) void gemm2_kernel(
    const float* __restrict__ h1, const float* __restrict__ W2,
    const float* __restrict__ dinv, float* __restrict__ gs, int N) {
    __shared__ float4 Ws[64 * 8];
    int t = threadIdx.x;
    const float4* W4 = (const float4*)W2;
    for (int i = t; i < 512; i += 256) Ws[i] = W4[i];
    __syncthreads();
    int ra = blockIdx.x * 512 + t;
    int rb = ra + 256;
    if (ra >= N) return;
    bool hb = rb < N;
    const float4* xa = (const float4*)(h1 + (size_t)ra * 64);
    const float4* xb = (const float4*)(h1 + (size_t)rb * 64);
    float4 acc0[8], acc1[8];
#pragma unroll
    for (int j = 0; j < 8; j++) {
        acc0[j] = make_float4(0.f, 0.f, 0.f, 0.f);
        acc1[j] = make_float4(0.f, 0.f, 0.f, 0.f);
    }
    for (int k4 = 0; k4 < 16; k4++) {
        float4 x0 = xa[k4];
        float4 x1 = hb ? xb[k4] : make_float4(0.f, 0.f, 0.f, 0.f);
#pragma unroll
        for (int kk = 0; kk < 4; kk++) {
            float a0 = ((const float*)&x0)[kk];
            float a1 = ((const float*)&x1)[kk];
            const float4* wr = &Ws[(k4 * 4 + kk) * 8];
#pragma unroll
            for (int j = 0; j < 8; j++) {
                float4 w = wr[j];
                acc0[j].x += a0 * w.x; acc0[j].y += a0 * w.y;
                acc0[j].z += a0 * w.z; acc0[j].w += a0 * w.w;
                acc1[j].x += a1 * w.x; acc1[j].y += a1 * w.y;
                acc1[j].z += a1 * w.z; acc1[j].w += a1 * w.w;
            }
        }
    }
    float d0 = dinv[ra];
    float4* ga = (float4*)(gs + (size_t)ra * 32);
#pragma unroll
    for (int j = 0; j < 8; j++) {
        float4 v = acc0[j];
        v.x *= d0; v.y *= d0; v.z *= d0; v.w *= d0;
        ga[j] = v;
    }
    if (hb) {
        float d1 = dinv[rb];
        float4* gb = (float4*)(gs + (size_t)rb * 32);
#pragma unroll
        for (int j = 0; j < 8; j++) {
            float4 v = acc1[j];
            v.x *= d1; v.y *= d1; v.z *= d1; v.w *= d1;
            gb[j] = v;
        }
    }
}

// Gather-aggregate layer 2: half-wave per node, lane = feature (32).
__global__ __launch_bounds__(256) void agg2_kernel(
    const float* __restrict__ gs, const int* __restrict__ ssrc,
    const int* __restrict__ off, const float* __restrict__ dinv,
    const float* __restrict__ b2, float* __restrict__ out, int N) {
    int w = (blockIdx.x * 256 + threadIdx.x) >> 5;
    int l = threadIdx.x & 31;
    if (w >= N) return;
    float acc = gs[(size_t)w * 32 + l];  // self-loop
    int lo = off[w], hi = off[w + 1];
    int e = lo;
    for (; e + 4 <= hi; e += 4) {
        int s0 = ssrc[e + 0];
        int s1 = ssrc[e + 1];
        int s2 = ssrc[e + 2];
        int s3 = ssrc[e + 3];
        float v0 = gs[(size_t)s0 * 32 + l];
        float v1 = gs[(size_t)s1 * 32 + l];
        float v2 = gs[(size_t)s2 * 32 + l];
        float v3 = gs[(size_t)s3 * 32 + l];
        acc += (v0 + v1) + (v2 + v3);
    }
    for (; e < hi; e++) {
        int s = ssrc[e];
        acc += gs[(size_t)s * 32 + l];
    }
    out[(size_t)w * 32 + l] = acc * dinv[w] + b2[l];
}

extern "C" void kernel_launch(void* const* d_in, const int* in_sizes, int n_in,
                              void* d_out, int out_size, void* d_ws,
                              size_t ws_size, hipStream_t stream) {
    const float* x  = (const float*)d_in[0];
    const int* ei   = (const int*)d_in[1];
    const float* W1 = (const float*)d_in[2];
    const float* b1 = (const float*)d_in[3];
    const float* W2 = (const float*)d_in[4];
    const float* b2 = (const float*)d_in[5];
    int N = in_sizes[0] / 64;
    int E = in_sizes[1] / 2;
    const int* src = ei;
    const int* dst = ei + E;
    int B = (N + BNODES - 1) >> BSHIFT;  // 391 for N=100000

    char* ws = (char*)d_ws;
    size_t o = 0;
    int* bcnt    = (int*)(ws + o); o += 512 * 4;
    int* base    = (int*)(ws + o); o += 513 * 4;
    int* cursor  = (int*)(ws + o); o += 512 * 4;
    int* off     = (int*)(ws + o); o += ((size_t)N + 1) * 4;
    float* dinv  = (float*)(ws + o); o += (size_t)N * 4;
    int* packed  = (int*)(ws + o); o += (size_t)E * 4;
    int* ssrc    = (int*)(ws + o); o += (size_t)E * 4;
    float* hs    = (float*)(ws + o); o += (size_t)N * 64 * 4;
    float* h1    = (float*)(ws + o); o += (size_t)N * 64 * 4;
    float* gs    = hs;  // hs dead after agg1; reuse (N*32)
    float* outp  = (float*)d_out;

    hipMemsetAsync(bcnt, 0, 512 * 4, stream);
    hist_kernel<<<(E + 4095) / 4096, 256, 0, stream>>>(dst, E, bcnt, B);
    scan_kernel<<<1, 512, 0, stream>>>(bcnt, base, cursor, off, B, E, N);
    scatter_kernel<<<(E + 255) / 256, 256, 0, stream>>>(src, dst, cursor,
                                                        packed, E);
    bsort_kernel<<<B, 256, 0, stream>>>(packed, base, ssrc, off, dinv, N);
    gemm1_kernel<<<(N + 511) / 512, 256, 0, stream>>>(x, W1, dinv, hs, N);
    agg1_kernel<<<(N * 64 + 255) / 256, 256, 0, stream>>>(hs, ssrc, off, dinv,
                                                          b1, h1, N);
    gemm2_kernel<<<(N + 511) / 512, 256, 0, stream>>>(h1, W2, dinv, gs, N);
    agg2_kernel<<<(N * 32 + 255) / 256, 256, 0, stream>>>(gs, ssrc, off, dinv,
                                                          b2, outp, N);
}

// Round 5
// 349.480 us; speedup vs baseline: 5.0800x; 2.4725x over previous
//
#include <hip/hip_runtime.h>

// GCN 2-layer. Pipeline:
//   blkhist -> offsets (decoupled, atomic-free) -> scatter2 (LDS cursors)
//   -> per-bucket LDS counting sort -> gemm1 -> gather-agg1 -> gemm2 -> gather-agg2
// History: R1 global fp32 atomics write through (400 MB). R2 per-node sort:
// 105 MB random scatter (131 us). R3 bucket-LDS-accumulate: 391-block grid,
// 14% occ (711 us). R4 bucket scatter: 391 contended cursors, 136 ns/atomic
// chains (557 us). This round: radix-partition with per-block precomputed
// offsets -- no contended atomics, block-disjoint write runs that merge in L2.

#define BSHIFT 8
#define BNODES 256
#define NB 256  // partition blocks

// Per-block bucket histogram: blkcnt[bin*NB + blk].
__global__ __launch_bounds__(256) void blkhist_kernel(
    const int* __restrict__ dst, int E, int* __restrict__ blkcnt, int B) {
    __shared__ int h[512];
    int t = threadIdx.x, b = blockIdx.x;
    for (int i = t; i < 512; i += 256) h[i] = 0;
    __syncthreads();
    int per = (E + NB - 1) / NB;
    int lo = b * per;
    int hi = min(lo + per, E);
    for (int i = lo + t; i < hi; i += 256) atomicAdd(&h[dst[i] >> BSHIFT], 1);
    __syncthreads();
    for (int i = t; i < B; i += 256) blkcnt[i * NB + b] = h[i];
}

// One block: in-place per-bucket exclusive scan across NB blocks, then
// exclusive scan of bucket totals -> base[]. Also off[N]=E, base[B]=E.
__global__ __launch_bounds__(512) void offsets_kernel(
    int* __restrict__ blkcnt, int* __restrict__ base, int* __restrict__ off,
    int B, int E, int N) {
    __shared__ int s[512];
    int t = threadIdx.x;
    int tot = 0;
    if (t < B) {
        int* row = blkcnt + (size_t)t * NB;
        int run = 0;
#pragma unroll 4
        for (int b = 0; b < NB; b++) {
            int c = row[b];
            row[b] = run;  // within-bucket block-exclusive prefix
            run += c;
        }
        tot = run;
    }
    s[t] = tot;
    __syncthreads();
#pragma unroll
    for (int d = 1; d < 512; d <<= 1) {
        int v = (t >= d) ? s[t - d] : 0;
        __syncthreads();
        s[t] += v;
        __syncthreads();
    }
    if (t < B) base[t] = s[t] - tot;  // bucket-exclusive prefix
    if (t == 0) {
        base[B] = E;
        off[N] = E;
    }
}

// Scatter via LDS cursors seeded from precomputed bases. No global atomics.
// Each block's writes are confined to its own disjoint runs per bucket.
__global__ __launch_bounds__(256) void scatter2_kernel(
    const int* __restrict__ src, const int* __restrict__ dst,
    const int* __restrict__ blkcnt, const int* __restrict__ base,
    int* __restrict__ packed, int E, int B) {
    __shared__ int cur[512];
    int t = threadIdx.x, b = blockIdx.x;
    for (int i = t; i < B; i += 256) cur[i] = base[i] + blkcnt[i * NB + b];
    __syncthreads();
    int per = (E + NB - 1) / NB;
    int lo = b * per;
    int hi = min(lo + per, E);
    for (int i = lo + t; i < hi; i += 256) {
        int d = dst[i];
        int pos = atomicAdd(&cur[d >> BSHIFT], 1);
        packed[pos] = (src[i] << BSHIFT) | (d & (BNODES - 1));
    }
}

// Per-bucket LDS counting sort -> ssrc grouped by node; also off & dinv.
// Writes stay in this bucket's own 16 KB window (L2-resident).
__global__ __launch_bounds__(256) void bsort_kernel(
    const int* __restrict__ packed, const int* __restrict__ base,
    int* __restrict__ ssrc, int* __restrict__ off, float* __restrict__ dinv,
    int N) {
    __shared__ int s[BNODES];
    __shared__ int cur[BNODES];
    int t = threadIdx.x, b = blockIdx.x;
    s[t] = 0;
    __syncthreads();
    int lo = base[b], hi = base[b + 1];
    for (int i = lo + t; i < hi; i += 256)
        atomicAdd(&s[packed[i] & (BNODES - 1)], 1);
    __syncthreads();
    int deg = s[t];
    __syncthreads();
    s[t] = deg;
    __syncthreads();
#pragma unroll
    for (int d = 1; d < BNODES; d <<= 1) {
        int v = (t >= d) ? s[t - d] : 0;
        __syncthreads();
        s[t] += v;
        __syncthreads();
    }
    int excl = s[t] - deg;
    cur[t] = excl;
    int node = (b << BSHIFT) + t;
    if (node < N) {
        off[node] = lo + excl;
        dinv[node] = rsqrtf((float)(deg + 1));
    }
    __syncthreads();
    for (int i = lo + t; i < hi; i += 256) {
        int p = packed[i];
        int pos = atomicAdd(&cur[p & (BNODES - 1)], 1);
        ssrc[lo + pos] = p >> BSHIFT;
    }
}

// hs = (x@W1)*dinv. 2 rows/thread, W1 broadcast from LDS.
__global__ __launch_bounds__(256) void gemm1_kernel(
    const float* __restrict__ x, const float* __restrict__ W1,
    const float* __restrict__ dinv, float* __restrict__ hs, int N) {
    __shared__ float4 Ws[64 * 16];
    int t = threadIdx.x;
    const float4* W4 = (const float4*)W1;
    for (int i = t; i < 1024; i += 256) Ws[i] = W4[i];
    __syncthreads();
    int ra = blockIdx.x * 512 + t;
    int rb = ra + 256;
    if (ra >= N) return;
    bool hb = rb < N;
    const float4* xa = (const float4*)(x + (size_t)ra * 64);
    const float4* xb = (const float4*)(x + (size_t)rb * 64);
    float4 acc0[16], acc1[16];
#pragma unroll
    for (int j = 0; j < 16; j++) {
        acc0[j] = make_float4(0.f, 0.f, 0.f, 0.f);
        acc1[j] = make_float4(0.f, 0.f, 0.f, 0.f);
    }
    for (int k4 = 0; k4 < 16; k4++) {
        float4 x0 = xa[k4];
        float4 x1 = hb ? xb[k4] : make_float4(0.f, 0.f, 0.f, 0.f);
#pragma unroll
        for (int kk = 0; kk < 4; kk++) {
            float a0 = ((const float*)&x0)[kk];
            float a1 = ((const float*)&x1)[kk];
            const float4* wr = &Ws[(k4 * 4 + kk) * 16];
#pragma unroll
            for (int j = 0; j < 16; j++) {
                float4 w = wr[j];
                acc0[j].x += a0 * w.x; acc0[j].y += a0 * w.y;
                acc0[j].z += a0 * w.z; acc0[j].w += a0 * w.w;
                acc1[j].x += a1 * w.x; acc1[j].y += a1 * w.y;
                acc1[j].z += a1 * w.z; acc1[j].w += a1 * w.w;
            }
        }
    }
    float d0 = dinv[ra];
    float4* ha = (float4*)(hs + (size_t)ra * 64);
#pragma unroll
    for (int j = 0; j < 16; j++) {
        float4 v = acc0[j];
        v.x *= d0; v.y *= d0; v.z *= d0; v.w *= d0;
        ha[j] = v;
    }
    if (hb) {
        float d1 = dinv[rb];
        float4* hb4 = (float4*)(hs + (size_t)rb * 64);
#pragma unroll
        for (int j = 0; j < 16; j++) {
            float4 v = acc1[j];
            v.x *= d1; v.y *= d1; v.z *= d1; v.w *= d1;
            hb4[j] = v;
        }
    }
}

// Gather-aggregate layer 1: wave per node, lane = feature (64).
__global__ __launch_bounds__(256) void agg1_kernel(
    const float* __restrict__ hs, const int* __restrict__ ssrc,
    const int* __restrict__ off, const float* __restrict__ dinv,
    const float* __restrict__ b1, float* __restrict__ h1, int N) {
    int w = (blockIdx.x * 256 + threadIdx.x) >> 6;
    int l = threadIdx.x & 63;
    if (w >= N) return;
    float acc = hs[(size_t)w * 64 + l];  // self-loop
    int lo = off[w], hi = off[w + 1];
    int e = lo;
    for (; e + 4 <= hi; e += 4) {
        int s0 = ssrc[e + 0];
        int s1 = ssrc[e + 1];
        int s2 = ssrc[e + 2];
        int s3 = ssrc[e + 3];
        float v0 = hs[(size_t)s0 * 64 + l];
        float v1 = hs[(size_t)s1 * 64 + l];
        float v2 = hs[(size_t)s2 * 64 + l];
        float v3 = hs[(size_t)s3 * 64 + l];
        acc += (v0 + v1) + (v2 + v3);
    }
    for (; e < hi; e++) {
        int s = ssrc[e];
        acc += hs[(size_t)s * 64 + l];
    }
    h1[(size_t)w * 64 + l] = fmaxf(acc * dinv[w] + b1[l], 0.f);
}

// gs = (h1@W2)*dinv. 2 rows/thread.
__global__ __launch_bounds__(256) void gemm2_kernel(
    const float* __restrict__ h1, const float* __restrict__ W2,
    const float* __restrict__ dinv, float* __restrict__ gs, int N) {
    __shared__ float4 Ws[64 * 8];
    int t = threadIdx.x;
    const float4* W4 = (const float4*)W2;
    for (int i = t; i < 512; i += 256) Ws[i] = W4[i];
    __syncthreads();
    int ra = blockIdx.x * 512 + t;
    int rb = ra + 256;
    if (ra >= N) return;
    bool hb = rb < N;
    const float4* xa = (const float4*)(h1 + (size_t)ra * 64);
    const float4* xb = (const float4*)(h1 + (size_t)rb * 64);
    float4 acc0[8], acc1[8];
#pragma unroll
    for (int j = 0; j < 8; j++) {
        acc0[j] = make_float4(0.f, 0.f, 0.f, 0.f);
        acc1[j] = make_float4(0.f, 0.f, 0.f, 0.f);
    }
    for (int k4 = 0; k4 < 16; k4++) {
        float4 x0 = xa[k4];
        float4 x1 = hb ? xb[k4] : make_float4(0.f, 0.f, 0.f, 0.f);
#pragma unroll
        for (int kk = 0; kk < 4; kk++) {
            float a0 = ((const float*)&x0)[kk];
            float a1 = ((const float*)&x1)[kk];
            const float4* wr = &Ws[(k4 * 4 + kk) * 8];
#pragma unroll
            for (int j = 0; j < 8; j++) {
                float4 w = wr[j];
                acc0[j].x += a0 * w.x; acc0[j].y += a0 * w.y;
                acc0[j].z += a0 * w.z; acc0[j].w += a0 * w.w;
                acc1[j].x += a1 * w.x; acc1[j].y += a1 * w.y;
                acc1[j].z += a1 * w.z; acc1[j].w += a1 * w.w;
            }
        }
    }
    float d0 = dinv[ra];
    float4* ga = (float4*)(gs + (size_t)ra * 32);
#pragma unroll
    for (int j = 0; j < 8; j++) {
        float4 v = acc0[j];
        v.x *= d0; v.y *= d0; v.z *= d0; v.w *= d0;
        ga[j] = v;
    }
    if (hb) {
        float d1 = dinv[rb];
        float4* gb = (float4*)(gs + (size_t)rb * 32);
#pragma unroll
        for (int j = 0; j < 8; j++) {
            float4 v = acc1[j];
            v.x *= d1; v.y *= d1; v.z *= d1; v.w *= d1;
            gb[j] = v;
        }
    }
}

// Gather-aggregate layer 2: half-wave per node, lane = feature (32).
__global__ __launch_bounds__(256) void agg2_kernel(
    const float* __restrict__ gs, const int* __restrict__ ssrc,
    const int* __restrict__ off, const float* __restrict__ dinv,
    const float* __restrict__ b2, float* __restrict__ out, int N) {
    int w = (blockIdx.x * 256 + threadIdx.x) >> 5;
    int l = threadIdx.x & 31;
    if (w >= N) return;
    float acc = gs[(size_t)w * 32 + l];  // self-loop
    int lo = off[w], hi = off[w + 1];
    int e = lo;
    for (; e + 4 <= hi; e += 4) {
        int s0 = ssrc[e + 0];
        int s1 = ssrc[e + 1];
        int s2 = ssrc[e + 2];
        int s3 = ssrc[e + 3];
        float v0 = gs[(size_t)s0 * 32 + l];
        float v1 = gs[(size_t)s1 * 32 + l];
        float v2 = gs[(size_t)s2 * 32 + l];
        float v3 = gs[(size_t)s3 * 32 + l];
        acc += (v0 + v1) + (v2 + v3);
    }
    for (; e < hi; e++) {
        int s = ssrc[e];
        acc += gs[(size_t)s * 32 + l];
    }
    out[(size_t)w * 32 + l] = acc * dinv[w] + b2[l];
}

extern "C" void kernel_launch(void* const* d_in, const int* in_sizes, int n_in,
                              void* d_out, int out_size, void* d_ws,
                              size_t ws_size, hipStream_t stream) {
    const float* x  = (const float*)d_in[0];
    const int* ei   = (const int*)d_in[1];
    const float* W1 = (const float*)d_in[2];
    const float* b1 = (const float*)d_in[3];
    const float* W2 = (const float*)d_in[4];
    const float* b2 = (const float*)d_in[5];
    int N = in_sizes[0] / 64;
    int E = in_sizes[1] / 2;
    const int* src = ei;
    const int* dst = ei + E;
    int B = (N + BNODES - 1) >> BSHIFT;  // 391 for N=100000

    char* ws = (char*)d_ws;
    size_t o = 0;
    int* blkcnt  = (int*)(ws + o); o += (size_t)512 * NB * 4;  // [bin][blk]
    int* base    = (int*)(ws + o); o += 513 * 4;
    int* off     = (int*)(ws + o); o += ((size_t)N + 1) * 4;
    float* dinv  = (float*)(ws + o); o += (size_t)N * 4;
    int* packed  = (int*)(ws + o); o += (size_t)E * 4;
    int* ssrc    = (int*)(ws + o); o += (size_t)E * 4;
    float* hs    = (float*)(ws + o); o += (size_t)N * 64 * 4;
    float* h1    = (float*)(ws + o); o += (size_t)N * 64 * 4;
    float* gs    = hs;  // hs dead after agg1; reuse (N*32)
    float* outp  = (float*)d_out;

    blkhist_kernel<<<NB, 256, 0, stream>>>(dst, E, blkcnt, B);
    offsets_kernel<<<1, 512, 0, stream>>>(blkcnt, base, off, B, E, N);
    scatter2_kernel<<<NB, 256, 0, stream>>>(src, dst, blkcnt, base, packed, E,
                                            B);
    bsort_kernel<<<B, 256, 0, stream>>>(packed, base, ssrc, off, dinv, N);
    gemm1_kernel<<<(N + 511) / 512, 256, 0, stream>>>(x, W1, dinv, hs, N);
    agg1_kernel<<<(N * 64 + 255) / 256, 256, 0, stream>>>(hs, ssrc, off, dinv,
                                                          b1, h1, N);
    gemm2_kernel<<<(N + 511) / 512, 256, 0, stream>>>(h1, W2, dinv, gs, N);
    agg2_kernel<<<(N * 32 + 255) / 256, 256, 0, stream>>>(gs, ssrc, off, dinv,
                                                          b2, outp, N);
}